// Round 8
// baseline (623.317 us; speedup 1.0000x reference)
//
#include <hip/hip_runtime.h>
#include <math.h>

#define Bsz 1024
#define Tt  128
#define Ff  32
#define Ee  16
#define Hh  20
#define Dd  4096
#define EPSc 1e-3f

// repacked fp32 weights per expert, gate-interleaved cols c = 4*u + g (g: i,f,g,o):
// K1p[32][80]@0, R1p[20][80]@2560, K2p[20][80]@4160, R2p[20][80]@5760,
// b1p[80]@7360, b2p[80]@7440  -> 7520 floats per expert
#define PWE 7520

typedef __attribute__((ext_vector_type(8))) short bf16x8;
typedef __attribute__((ext_vector_type(4))) float f32x4;

#define MFMA16(a,b,c) __builtin_amdgcn_mfma_f32_16x16x32_bf16(a, b, c, 0, 0, 0)

__device__ __forceinline__ float sigmoidf_(float x) {
    return 1.0f / (1.0f + __expf(-x));
}
__device__ __forceinline__ unsigned short bf16_rne(float f) {
    unsigned u = __float_as_uint(f);
    u += 0x7FFFu + ((u >> 16) & 1u);
    return (unsigned short)(u >> 16);
}
__device__ __forceinline__ float bf16_to_f(unsigned short h) {
    return __uint_as_float(((unsigned)h) << 16);
}
// truncation split: f = hi + lo with hi = trunc16(f)
__device__ __forceinline__ void split8(const float* v, bf16x8& hv, bf16x8& lv) {
#pragma unroll
    for (int j = 0; j < 8; ++j) {
        unsigned u = __float_as_uint(v[j]);
        hv[j] = (short)(unsigned short)(u >> 16);
        float hf = __uint_as_float(u & 0xFFFF0000u);
        lv[j] = (short)bf16_rne(v[j] - hf);
    }
}

// ---------------------------------------------------------------- x prepass: BN + bf16 hi/lo split
// B-fragment layout: elem (c,t,l)*8+j holds xn[b=c*16+(l&15)][t][f=(l>>4)*8+j]
__global__ void xpack_kernel(const float* __restrict__ x,
                             const float* __restrict__ gamma, const float* __restrict__ beta,
                             const float* __restrict__ mean,  const float* __restrict__ var,
                             unsigned short* __restrict__ xph, unsigned short* __restrict__ xpl)
{
    __shared__ float sc[Ff], sh[Ff];
    int tid = threadIdx.x;
    if (tid < Ff) {
        float s = gamma[tid] * rsqrtf(var[tid] + EPSc);
        sc[tid] = s;
        sh[tid] = beta[tid] - mean[tid] * s;
    }
    __syncthreads();
    int idx = blockIdx.x * 256 + tid;           // 0 .. 64*128*64-1
    int c   = idx >> 13;
    int rem = idx & 8191;
    int t   = rem >> 6;
    int l   = rem & 63;
    int q   = l >> 4, s = l & 15;
    const float* xr = x + ((size_t)(c * 16 + s) * Tt + t) * Ff + q * 8;
    float4 v0 = *(const float4*)xr;
    float4 v1 = *(const float4*)(xr + 4);
    float xv[8] = {v0.x, v0.y, v0.z, v0.w, v1.x, v1.y, v1.z, v1.w};
    bf16x8 hv, lv;
#pragma unroll
    for (int j = 0; j < 8; ++j) {
        int f = q * 8 + j;
        float xn_ = xv[j] * sc[f] + sh[f];
        unsigned short hi = bf16_rne(xn_);
        hv[j] = (short)hi;
        lv[j] = (short)bf16_rne(xn_ - bf16_to_f(hi));
    }
    *(bf16x8*)(xph + (size_t)idx * 8) = hv;
    *(bf16x8*)(xpl + (size_t)idx * 8) = lv;
}

// ---------------------------------------------------------------- weight repack (gate-interleave)
__global__ void repack2_kernel(const float* __restrict__ k1, const float* __restrict__ r1,
                               const float* __restrict__ b1, const float* __restrict__ k2,
                               const float* __restrict__ r2, const float* __restrict__ b2,
                               float* __restrict__ pw)
{
    int idx = blockIdx.x * blockDim.x + threadIdx.x;
    if (idx >= Ee * PWE) return;
    int e = idx / PWE;
    int o = idx % PWE;
    float v;
    if (o < 7360) {
        int c = o % 80, u = c >> 2, g = c & 3;
        int co = g * 20 + u;
        if (o < 2560) {
            int kk = o / 80;
            v = k1[((size_t)e * Ff + kk) * 80 + co];
        } else if (o < 4160) {
            int kk = (o - 2560) / 80;
            v = r1[((size_t)e * Hh + kk) * 80 + co];
        } else if (o < 5760) {
            int kk = (o - 4160) / 80;
            v = k2[((size_t)e * Hh + kk) * 80 + co];
        } else {
            int kk = (o - 5760) / 80;
            v = r2[((size_t)e * Hh + kk) * 80 + co];
        }
    } else if (o < 7440) {
        int c = o - 7360, u = c >> 2, g = c & 3;
        v = b1[(size_t)e * 80 + g * 20 + u];
    } else {
        int c = o - 7440, u = c >> 2, g = c & 3;
        v = b2[(size_t)e * 80 + g * 20 + u];
    }
    pw[idx] = v;
}

// ---------------------------------------------------------------- fused lstm + fc1
// 512 blocks x 256 thr, 2 blocks/CU -> each SIMD: 1 lstm wave + 1 fc1 wave.
// LSTM (waves 0-1): z^T = W^T(A-frag) @ act(B-frag) -> gates land in acc REGS
// (reg r = gate r of unit 4n+q, col s = batch) -> elementwise with NO z LDS
// roundtrip. Two-layer software pipeline: iter t computes L2(t) and L1(t+1)
// together (both depend only on h1(t)) -> serial LDS segments per t: 8 -> ~3.
// fc1 (waves 2-3): LDS-free 64x64 split-bf16 tiles (unchanged from R7).
#define TILE_LDS 5120
__global__ __launch_bounds__(256, 2) void fused_kernel(
    const unsigned short* __restrict__ xph, const unsigned short* __restrict__ xpl,
    const float* __restrict__ pw, const float* __restrict__ dw, const float* __restrict__ db,
    float* __restrict__ eo,
    const float* __restrict__ x, const float* __restrict__ W,
    const float* __restrict__ bias, float* __restrict__ C)
{
    __shared__ __align__(16) char smem[2 * TILE_LDS];

    const int w = threadIdx.x >> 6;
    const int l = threadIdx.x & 63;
    const int q = l >> 4, s = l & 15;

    if (w < 2) {
        // ================= LSTM path: wave w handles tile blockIdx*2+w =================
        const int tile = blockIdx.x * 2 + w;
        const int e = tile >> 6;
        const int c = tile & 63;
        const int b0 = c * 16;

        // h state, [batch][unit] u16, row stride 40 (units 20..39 stay zero:
        // padding for q-frag reads; zero weights cover k>=20 anyway)
        short* h1h = (short*)(smem + w * TILE_LDS);   // 640 u16 each
        short* h1l = h1h + 640;
        short* h2h = h1l + 640;
        short* h2l = h2h + 640;
        {
            int* hz = (int*)h1h;
            for (int i = l; i < 1280; i += 64) hz[i] = 0;
        }

        const float* Wm = pw + (size_t)e * PWE;
        bf16x8 K1h[5], K1l[5], R1h[5], R1l[5], K2h[5], K2l[5], R2h[5], R2l[5];
#pragma unroll
        for (int n = 0; n < 5; ++n) {
#pragma unroll
            for (int j = 0; j < 8; ++j) {
                int k = q * 8 + j;
                int cc = n * 16 + s;
                float wv_;
                unsigned short hi; float hf;
                wv_ = Wm[k * 80 + cc];
                hi = bf16_rne(wv_); hf = bf16_to_f(hi);
                K1h[n][j] = (short)hi; K1l[n][j] = (short)bf16_rne(wv_ - hf);
                wv_ = (k < Hh) ? Wm[2560 + k * 80 + cc] : 0.f;
                hi = bf16_rne(wv_); hf = bf16_to_f(hi);
                R1h[n][j] = (short)hi; R1l[n][j] = (short)bf16_rne(wv_ - hf);
                wv_ = (k < Hh) ? Wm[4160 + k * 80 + cc] : 0.f;
                hi = bf16_rne(wv_); hf = bf16_to_f(hi);
                K2h[n][j] = (short)hi; K2l[n][j] = (short)bf16_rne(wv_ - hf);
                wv_ = (k < Hh) ? Wm[5760 + k * 80 + cc] : 0.f;
                hi = bf16_rne(wv_); hf = bf16_to_f(hi);
                R2h[n][j] = (short)hi; R2l[n][j] = (short)bf16_rne(wv_ - hf);
            }
        }
        // biases: lane (q,s) needs cols n*16+4q..+3 -> contiguous float4
        f32x4 b1v[5], b2v[5];
        float dwr[5];
#pragma unroll
        for (int n = 0; n < 5; ++n) {
            b1v[n] = *(const f32x4*)&Wm[7360 + n * 16 + 4 * q];
            b2v[n] = *(const f32x4*)&Wm[7440 + n * 16 + 4 * q];
            dwr[n] = dw[e * Hh + 4 * n + q];
        }

        float c1s[5] = {0, 0, 0, 0, 0}, c2s[5] = {0, 0, 0, 0, 0};

        const unsigned short* xbh = xph + (size_t)c * 65536 + l * 8;
        const unsigned short* xbl = xpl + (size_t)c * 65536 + l * 8;
        const int hoff = s * 40 + q * 8;      // B-frag read offset (u16)
        const int woff = s * 40 + 4 * 0 + q;  // base for h writes (u16), + 4n

        // ---- prologue: L1 step 0 (h1(-1)=0 -> K1 terms only) -> h1(0)
        {
            bf16x8 x0h = *(const bf16x8*)xbh;
            bf16x8 x0l = *(const bf16x8*)xbl;
#pragma unroll
            for (int n = 0; n < 5; ++n) {
                f32x4 A1 = b1v[n];
                A1 = MFMA16(K1l[n], x0h, A1);
                A1 = MFMA16(K1h[n], x0l, A1);
                A1 = MFMA16(K1h[n], x0h, A1);
                float iv = sigmoidf_(A1[0]);
                float fv = sigmoidf_(A1[1]);
                float gv = fmaxf(A1[2], 0.f);
                float ov = sigmoidf_(A1[3]);
                c1s[n] = fv * c1s[n] + iv * gv;
                float h = ov * fmaxf(c1s[n], 0.f);
                unsigned u = __float_as_uint(h);
                h1h[woff + 4 * n] = (short)(unsigned short)(u >> 16);
                h1l[woff + 4 * n] = (short)bf16_rne(h - __uint_as_float(u & 0xFFFF0000u));
            }
        }
        bf16x8 xch = *(const bf16x8*)(xbh + 512);   // x(1)
        bf16x8 xcl = *(const bf16x8*)(xbl + 512);

        // ---- main loop: iter t computes L2(t) [h1(t), h2(t-1)] and L1(t+1) [x(t+1), h1(t)]
#pragma unroll 1
        for (int t = 0; t < Tt - 1; ++t) {
            bf16x8 H1A = *(bf16x8*)&h1h[hoff];
            bf16x8 H1B = *(bf16x8*)&h1l[hoff];
            bf16x8 H2A = *(bf16x8*)&h2h[hoff];
            bf16x8 H2B = *(bf16x8*)&h2l[hoff];

            bf16x8 xnh = xch, xnl = xcl;
            if (t < Tt - 2) {   // prefetch x(t+2)
                xnh = *(const bf16x8*)(xbh + (t + 2) * 512);
                xnl = *(const bf16x8*)(xbl + (t + 2) * 512);
            }

            f32x4 a1[5], a2[5];
#pragma unroll
            for (int n = 0; n < 5; ++n) {
                f32x4 A1 = b1v[n];
                A1 = MFMA16(K1l[n], xch, A1);
                A1 = MFMA16(K1h[n], xcl, A1);
                A1 = MFMA16(K1h[n], xch, A1);
                A1 = MFMA16(R1l[n], H1A, A1);
                A1 = MFMA16(R1h[n], H1B, A1);
                A1 = MFMA16(R1h[n], H1A, A1);
                a1[n] = A1;
                f32x4 A2 = b2v[n];
                A2 = MFMA16(K2l[n], H1A, A2);
                A2 = MFMA16(K2h[n], H1B, A2);
                A2 = MFMA16(K2h[n], H1A, A2);
                A2 = MFMA16(R2l[n], H2A, A2);
                A2 = MFMA16(R2h[n], H2B, A2);
                A2 = MFMA16(R2h[n], H2A, A2);
                a2[n] = A2;
            }
#pragma unroll
            for (int n = 0; n < 5; ++n) {
                {   // layer 2 -> h2(t)
                    f32x4 z = a2[n];
                    float iv = sigmoidf_(z[0]);
                    float fv = sigmoidf_(z[1]);
                    float gv = fmaxf(z[2], 0.f);
                    float ov = sigmoidf_(z[3]);
                    c2s[n] = fv * c2s[n] + iv * gv;
                    float h = ov * fmaxf(c2s[n], 0.f);
                    unsigned u = __float_as_uint(h);
                    h2h[woff + 4 * n] = (short)(unsigned short)(u >> 16);
                    h2l[woff + 4 * n] = (short)bf16_rne(h - __uint_as_float(u & 0xFFFF0000u));
                }
                {   // layer 1 -> h1(t+1)
                    f32x4 z = a1[n];
                    float iv = sigmoidf_(z[0]);
                    float fv = sigmoidf_(z[1]);
                    float gv = fmaxf(z[2], 0.f);
                    float ov = sigmoidf_(z[3]);
                    c1s[n] = fv * c1s[n] + iv * gv;
                    float h = ov * fmaxf(c1s[n], 0.f);
                    unsigned u = __float_as_uint(h);
                    h1h[woff + 4 * n] = (short)(unsigned short)(u >> 16);
                    h1l[woff + 4 * n] = (short)bf16_rne(h - __uint_as_float(u & 0xFFFF0000u));
                }
            }
            xch = xnh; xcl = xnl;
        }

        // ---- epilogue: L2 step T-1 -> h2(T-1) in regs -> dense head
        {
            bf16x8 H1A = *(bf16x8*)&h1h[hoff];
            bf16x8 H1B = *(bf16x8*)&h1l[hoff];
            bf16x8 H2A = *(bf16x8*)&h2h[hoff];
            bf16x8 H2B = *(bf16x8*)&h2l[hoff];
            float p = 0.f;
#pragma unroll
            for (int n = 0; n < 5; ++n) {
                f32x4 A2 = b2v[n];
                A2 = MFMA16(K2l[n], H1A, A2);
                A2 = MFMA16(K2h[n], H1B, A2);
                A2 = MFMA16(K2h[n], H1A, A2);
                A2 = MFMA16(R2l[n], H2A, A2);
                A2 = MFMA16(R2h[n], H2B, A2);
                A2 = MFMA16(R2h[n], H2A, A2);
                float iv = sigmoidf_(A2[0]);
                float fv = sigmoidf_(A2[1]);
                float gv = fmaxf(A2[2], 0.f);
                float ov = sigmoidf_(A2[3]);
                c2s[n] = fv * c2s[n] + iv * gv;
                p += ov * fmaxf(c2s[n], 0.f) * dwr[n];
            }
            p += __shfl_xor(p, 16);
            p += __shfl_xor(p, 32);
            if (q == 0) eo[(size_t)e * Bsz + b0 + s] = db[e] + p;
        }

    } else {
        // ================= fc1 path: one 64x64 tile per wave, LDS-free =================
        const int fid = blockIdx.x * 2 + (w - 2);
        const int m0 = (fid >> 6) * 64;
        const int n0 = (fid & 63) * 64;

        f32x4 acc[4][4];
#pragma unroll
        for (int mt = 0; mt < 4; ++mt)
#pragma unroll
            for (int nt = 0; nt < 4; ++nt) acc[mt][nt] = (f32x4){0.f, 0.f, 0.f, 0.f};

        const float* Arow[4];
#pragma unroll
        for (int mt = 0; mt < 4; ++mt)
            Arow[mt] = x + (size_t)(m0 + mt * 16 + s) * Dd + q * 8;
        const float* Wbase = W + (size_t)(q * 8) * Dd + n0 + s;

#pragma unroll 1
        for (int k0 = 0; k0 < Dd; k0 += 32) {
            float av[4][8];
#pragma unroll
            for (int mt = 0; mt < 4; ++mt) {
                *(float4*)&av[mt][0] = *(const float4*)(Arow[mt] + k0);
                *(float4*)&av[mt][4] = *(const float4*)(Arow[mt] + k0 + 4);
            }
            float wv[4][8];
#pragma unroll
            for (int j = 0; j < 8; ++j) {
                const float* wr = Wbase + (size_t)(k0 + j) * Dd;
#pragma unroll
                for (int nt = 0; nt < 4; ++nt) wv[nt][j] = wr[nt * 16];
            }
            bf16x8 Afh[4], Afl[4], Wfh[4], Wfl[4];
#pragma unroll
            for (int mt = 0; mt < 4; ++mt) split8(av[mt], Afh[mt], Afl[mt]);
#pragma unroll
            for (int nt = 0; nt < 4; ++nt) split8(wv[nt], Wfh[nt], Wfl[nt]);
#pragma unroll
            for (int mt = 0; mt < 4; ++mt)
#pragma unroll
                for (int nt = 0; nt < 4; ++nt) {
                    f32x4 a = acc[mt][nt];
                    a = MFMA16(Afl[mt], Wfh[nt], a);
                    a = MFMA16(Afh[mt], Wfl[nt], a);
                    a = MFMA16(Afh[mt], Wfh[nt], a);
                    acc[mt][nt] = a;
                }
        }

#pragma unroll
        for (int nt = 0; nt < 4; ++nt) {
            float bv = bias[n0 + nt * 16 + s];
#pragma unroll
            for (int mt = 0; mt < 4; ++mt)
#pragma unroll
                for (int r = 0; r < 4; ++r) {
                    int m = m0 + mt * 16 + q * 4 + r;
                    C[(size_t)m * Dd + n0 + nt * 16 + s] = fmaxf(acc[mt][nt][r] + bv, 0.f);
                }
        }
    }
}

// ---------------------------------------------------------------- gate: softmax(g @ gate_w + gb) + combine
__global__ __launch_bounds__(256) void gate_kernel(const float* __restrict__ g,
                                                   const float* __restrict__ gw,
                                                   const float* __restrict__ gb,
                                                   const float* __restrict__ eo,
                                                   float* __restrict__ out)
{
    int b = blockIdx.x;
    int tid = threadIdx.x;
    int lane = tid & 63;
    int wv = tid >> 6;

    float acc[16];
#pragma unroll
    for (int j = 0; j < 16; ++j) acc[j] = 0.f;

    const float* grow = g + (size_t)b * Dd;
#pragma unroll
    for (int it = 0; it < Dd / 256; ++it) {
        int d = tid + it * 256;
        float gv = grow[d];
        const float4* wr = (const float4*)(gw + (size_t)d * 16);
        float4 w0 = wr[0], w1 = wr[1], w2 = wr[2], w3 = wr[3];
        acc[0] += gv * w0.x;  acc[1] += gv * w0.y;  acc[2] += gv * w0.z;  acc[3] += gv * w0.w;
        acc[4] += gv * w1.x;  acc[5] += gv * w1.y;  acc[6] += gv * w1.z;  acc[7] += gv * w1.w;
        acc[8] += gv * w2.x;  acc[9] += gv * w2.y;  acc[10] += gv * w2.z; acc[11] += gv * w2.w;
        acc[12] += gv * w3.x; acc[13] += gv * w3.y; acc[14] += gv * w3.z; acc[15] += gv * w3.w;
    }

    __shared__ float red[64];
    __shared__ float logits[16];
#pragma unroll
    for (int j = 0; j < 16; ++j) {
        float v = acc[j];
#pragma unroll
        for (int m = 32; m >= 1; m >>= 1) v += __shfl_xor(v, m);
        if (lane == 0) red[wv * 16 + j] = v;
    }
    __syncthreads();
    if (tid < 16) {
        logits[tid] = gb[tid] + red[tid] + red[16 + tid] + red[32 + tid] + red[48 + tid];
    }
    __syncthreads();
    if (tid == 0) {
        float m = logits[0];
#pragma unroll
        for (int j = 1; j < 16; ++j) m = fmaxf(m, logits[j]);
        float ex[16], ssum = 0.f;
#pragma unroll
        for (int j = 0; j < 16; ++j) { ex[j] = __expf(logits[j] - m); ssum += ex[j]; }
        float inv = 1.f / ssum;
        float o = 0.f;
#pragma unroll
        for (int j = 0; j < 16; ++j) o += ex[j] * inv * eo[(size_t)j * Bsz + b];
        out[b] = o;
    }
}

// ----------------------------------------------------------------
extern "C" void kernel_launch(void* const* d_in, const int* in_sizes, int n_in,
                              void* d_out, int out_size, void* d_ws, size_t ws_size,
                              hipStream_t stream)
{
    const float* x     = (const float*)d_in[0];
    const float* gamma = (const float*)d_in[1];
    const float* beta  = (const float*)d_in[2];
    const float* mean  = (const float*)d_in[3];
    const float* var   = (const float*)d_in[4];
    const float* k1    = (const float*)d_in[5];
    const float* r1    = (const float*)d_in[6];
    const float* b1    = (const float*)d_in[7];
    const float* k2    = (const float*)d_in[8];
    const float* r2    = (const float*)d_in[9];
    const float* b2    = (const float*)d_in[10];
    const float* dw    = (const float*)d_in[11];
    const float* db    = (const float*)d_in[12];
    const float* fc1w  = (const float*)d_in[13];
    const float* fc1b  = (const float*)d_in[14];
    const float* gw    = (const float*)d_in[15];
    const float* gb    = (const float*)d_in[16];
    float* out = (float*)d_out;

    // workspace: 33.1 MB
    float* g = (float*)d_ws;                                        // 4,194,304 f (16 MB)
    unsigned short* xph = (unsigned short*)(g + (size_t)Bsz * Dd);  // 8 MB
    unsigned short* xpl = xph + (size_t)4194304;                    // 8 MB
    float* pw  = (float*)(xpl + (size_t)4194304);                   // 120,320 f
    float* eo  = pw + (size_t)Ee * PWE;                             // 16,384 f

    xpack_kernel<<<2048, 256, 0, stream>>>(x, gamma, beta, mean, var, xph, xpl);
    repack2_kernel<<<(Ee * PWE + 255) / 256, 256, 0, stream>>>(k1, r1, b1, k2, r2, b2, pw);
    fused_kernel<<<512, 256, 0, stream>>>(xph, xpl, pw, dw, db, eo, x, fc1w, fc1b, g);
    gate_kernel<<<Bsz, 256, 0, stream>>>(g, gw, gb, eo, out);
}

// Round 9
// 604.865 us; speedup vs baseline: 1.0305x; 1.0305x over previous
//
#include <hip/hip_runtime.h>
#include <math.h>

#define Bsz 1024
#define Tt  128
#define Ff  32
#define Ee  16
#define Hh  20
#define Dd  4096
#define EPSc 1e-3f

// repacked fp32 weights per expert, gate-interleaved cols c = 4*u + g (g: i,f,g,o):
// K1p[32][80]@0, R1p[20][80]@2560, K2p[20][80]@4160, R2p[20][80]@5760,
// b1p[80]@7360, b2p[80]@7440  -> 7520 floats per expert
#define PWE 7520

typedef __attribute__((ext_vector_type(8))) short bf16x8;
typedef __attribute__((ext_vector_type(4))) float f32x4;

#define MFMA16(a,b,c) __builtin_amdgcn_mfma_f32_16x16x32_bf16(a, b, c, 0, 0, 0)

__device__ __forceinline__ float sigmoidf_(float x) {
    return 1.0f / (1.0f + __expf(-x));
}
__device__ __forceinline__ unsigned short bf16_rne(float f) {
    unsigned u = __float_as_uint(f);
    u += 0x7FFFu + ((u >> 16) & 1u);
    return (unsigned short)(u >> 16);
}
__device__ __forceinline__ float bf16_to_f(unsigned short h) {
    return __uint_as_float(((unsigned)h) << 16);
}
// truncation split for fc1 (f = hi + lo, hi = trunc16(f))
__device__ __forceinline__ void split8(const float* v, bf16x8& hv, bf16x8& lv) {
#pragma unroll
    for (int j = 0; j < 8; ++j) {
        unsigned u = __float_as_uint(v[j]);
        hv[j] = (short)(unsigned short)(u >> 16);
        float hf = __uint_as_float(u & 0xFFFF0000u);
        lv[j] = (short)bf16_rne(v[j] - hf);
    }
}

// ---------------------------------------------------------------- x prepass: BN + bf16 hi/lo split
// B-fragment layout: elem (c,t,l)*8+j holds xn[b=c*16+(l&15)][t][f=(l>>4)*8+j]
__global__ void xpack_kernel(const float* __restrict__ x,
                             const float* __restrict__ gamma, const float* __restrict__ beta,
                             const float* __restrict__ mean,  const float* __restrict__ var,
                             unsigned short* __restrict__ xph, unsigned short* __restrict__ xpl)
{
    __shared__ float sc[Ff], sh[Ff];
    int tid = threadIdx.x;
    if (tid < Ff) {
        float s = gamma[tid] * rsqrtf(var[tid] + EPSc);
        sc[tid] = s;
        sh[tid] = beta[tid] - mean[tid] * s;
    }
    __syncthreads();
    int idx = blockIdx.x * 256 + tid;           // 0 .. 64*128*64-1
    int c   = idx >> 13;
    int rem = idx & 8191;
    int t   = rem >> 6;
    int l   = rem & 63;
    int q   = l >> 4, s = l & 15;
    const float* xr = x + ((size_t)(c * 16 + s) * Tt + t) * Ff + q * 8;
    float4 v0 = *(const float4*)xr;
    float4 v1 = *(const float4*)(xr + 4);
    float xv[8] = {v0.x, v0.y, v0.z, v0.w, v1.x, v1.y, v1.z, v1.w};
    bf16x8 hv, lv;
#pragma unroll
    for (int j = 0; j < 8; ++j) {
        int f = q * 8 + j;
        float xn_ = xv[j] * sc[f] + sh[f];
        unsigned short hi = bf16_rne(xn_);
        hv[j] = (short)hi;
        lv[j] = (short)bf16_rne(xn_ - bf16_to_f(hi));
    }
    *(bf16x8*)(xph + (size_t)idx * 8) = hv;
    *(bf16x8*)(xpl + (size_t)idx * 8) = lv;
}

// ---------------------------------------------------------------- weight repack (gate-interleave)
__global__ void repack2_kernel(const float* __restrict__ k1, const float* __restrict__ r1,
                               const float* __restrict__ b1, const float* __restrict__ k2,
                               const float* __restrict__ r2, const float* __restrict__ b2,
                               float* __restrict__ pw)
{
    int idx = blockIdx.x * blockDim.x + threadIdx.x;
    if (idx >= Ee * PWE) return;
    int e = idx / PWE;
    int o = idx % PWE;
    float v;
    if (o < 7360) {
        int c = o % 80, u = c >> 2, g = c & 3;
        int co = g * 20 + u;
        if (o < 2560) {
            int kk = o / 80;
            v = k1[((size_t)e * Ff + kk) * 80 + co];
        } else if (o < 4160) {
            int kk = (o - 2560) / 80;
            v = r1[((size_t)e * Hh + kk) * 80 + co];
        } else if (o < 5760) {
            int kk = (o - 4160) / 80;
            v = k2[((size_t)e * Hh + kk) * 80 + co];
        } else {
            int kk = (o - 5760) / 80;
            v = r2[((size_t)e * Hh + kk) * 80 + co];
        }
    } else if (o < 7440) {
        int c = o - 7360, u = c >> 2, g = c & 3;
        v = b1[(size_t)e * 80 + g * 20 + u];
    } else {
        int c = o - 7440, u = c >> 2, g = c & 3;
        v = b2[(size_t)e * 80 + g * 20 + u];
    }
    pw[idx] = v;
}

// ---------------------------------------------------------------- fused lstm + fc1
// 512 blocks x 256 thr (2 blocks/CU). Waves 0-1: lstm tiles (same expert per
// block). ALL 40 weight B-op frags live in LDS (staged once, 40 KB shared) and
// are streamed per-MFMA via ds_read_b128 at loop-invariant addresses -> true
// VGPR demand ~120, no compiler remat/spill of the weight set (the R4-R8
// hidden bottleneck). Waves 2-3: LDS-free 64x64 fc1 tiles (unchanged).
__global__ __launch_bounds__(256, 2) void fused_kernel(
    const unsigned short* __restrict__ xph, const unsigned short* __restrict__ xpl,
    const float* __restrict__ pw, const float* __restrict__ dw, const float* __restrict__ db,
    float* __restrict__ eo,
    const float* __restrict__ x, const float* __restrict__ W,
    const float* __restrict__ bias, float* __restrict__ C)
{
    // frag f (0..39) at wfr[f*512 + lane*8], 16B per lane per frag.
    // f: 0-4 K1h(n), 5-9 K1l, 10-14 R1h, 15-19 R1l, 20-24 K2h, 25-29 K2l,
    //    30-34 R2h, 35-39 R2l
    __shared__ short wfr[40 * 512];           // 40960 B
    __shared__ short hst[2][4 * 640];         // 2 tiles x (h1h,h1l,h2h,h2l) = 10240 B

    const int w = threadIdx.x >> 6;
    const int l = threadIdx.x & 63;
    const int q = l >> 4, s = l & 15;

    const int e = blockIdx.x >> 5;            // 32 blocks per expert

    if (w < 2) {
        // ---- zero h state for tile w
        int* hz = (int*)&hst[w][0];
        for (int i = l; i < 1280; i += 64) hz[i] = 0;
        // ---- stage 20 weight frags (wave w: frags 20w..20w+19)
        const float* Wm = pw + (size_t)e * PWE;
#pragma unroll
        for (int g = 0; g < 20; ++g) {
            int fid = w * 20 + g;
            int n = fid % 5;
            int m = fid / 5;        // 0 K1h 1 K1l 2 R1h 3 R1l 4 K2h 5 K2l 6 R2h 7 R2l
            int mat = m >> 1, lo = m & 1;
            int base = (mat == 0) ? 0 : (mat == 1) ? 2560 : (mat == 2) ? 4160 : 5760;
            bf16x8 outv;
#pragma unroll
            for (int j = 0; j < 8; ++j) {
                int k = q * 8 + j;
                int cc = n * 16 + s;
                float v = (mat == 0 || k < Hh) ? Wm[base + k * 80 + cc] : 0.f;
                unsigned short hi = bf16_rne(v);
                outv[j] = lo ? (short)bf16_rne(v - bf16_to_f(hi)) : (short)hi;
            }
            *(bf16x8*)&wfr[fid * 512 + l * 8] = outv;
        }
    }
    __syncthreads();    // weights + h-state visible; fc1 waves pass through

    if (w < 2) {
        // ================= LSTM path: wave w, tile (blockIdx&31)*2+w of expert e ====
        const int c = (blockIdx.x & 31) * 2 + w;
        const int b0 = c * 16;

        short* h1h = &hst[w][0];
        short* h1l = h1h + 640;
        short* h2h = h1l + 640;
        short* h2l = h2h + 640;
        const short* wl = &wfr[l * 8];     // per-lane frag base; frag f at +f*512
#define FR(f) (*(const bf16x8*)(wl + (f) * 512))

        const float* Wm = pw + (size_t)e * PWE;
        f32x4 b1v[5], b2v[5];
        float dwr[5];
#pragma unroll
        for (int n = 0; n < 5; ++n) {
            b1v[n] = *(const f32x4*)&Wm[7360 + n * 16 + 4 * q];
            b2v[n] = *(const f32x4*)&Wm[7440 + n * 16 + 4 * q];
            dwr[n] = dw[e * Hh + 4 * n + q];
        }

        float c1s[5] = {0, 0, 0, 0, 0}, c2s[5] = {0, 0, 0, 0, 0};

        const unsigned short* xbh = xph + (size_t)c * 65536 + l * 8;
        const unsigned short* xbl = xpl + (size_t)c * 65536 + l * 8;
        const int hoff = s * 40 + q * 8;      // B-frag read offset (u16)
        const int woff = s * 40 + q;          // h write base (u16), + 4n

        // ---- prologue: L1 step 0 (h1(-1)=0) -> h1(0)
        {
            bf16x8 x0h = *(const bf16x8*)xbh;
            bf16x8 x0l = *(const bf16x8*)xbl;
#pragma unroll
            for (int n = 0; n < 5; ++n) {
                f32x4 A1 = b1v[n];
                A1 = MFMA16(FR(5 + n), x0h, A1);
                A1 = MFMA16(FR(n),     x0l, A1);
                A1 = MFMA16(FR(n),     x0h, A1);
                float iv = sigmoidf_(A1[0]);
                float fv = sigmoidf_(A1[1]);
                float gv = fmaxf(A1[2], 0.f);
                float ov = sigmoidf_(A1[3]);
                c1s[n] = fv * c1s[n] + iv * gv;
                float h = ov * fmaxf(c1s[n], 0.f);
                unsigned u = __float_as_uint(h);
                h1h[woff + 4 * n] = (short)(unsigned short)(u >> 16);
                h1l[woff + 4 * n] = (short)bf16_rne(h - __uint_as_float(u & 0xFFFF0000u));
            }
        }
        bf16x8 xch = *(const bf16x8*)(xbh + 512);   // x(1)
        bf16x8 xcl = *(const bf16x8*)(xbl + 512);

        // ---- main loop: iter t computes L2(t) and L1(t+1) (both need only h1(t))
#pragma unroll 1
        for (int t = 0; t < Tt - 1; ++t) {
            bf16x8 H1A = *(bf16x8*)&h1h[hoff];
            bf16x8 H1B = *(bf16x8*)&h1l[hoff];
            bf16x8 H2A = *(bf16x8*)&h2h[hoff];
            bf16x8 H2B = *(bf16x8*)&h2l[hoff];

            bf16x8 xnh = xch, xnl = xcl;
            if (t < Tt - 2) {   // prefetch x(t+2)
                xnh = *(const bf16x8*)(xbh + (t + 2) * 512);
                xnl = *(const bf16x8*)(xbl + (t + 2) * 512);
            }

#pragma unroll
            for (int n = 0; n < 5; ++n) {
                f32x4 A1 = b1v[n];
                A1 = MFMA16(FR(5 + n),  xch, A1);    // K1l*xh
                A1 = MFMA16(FR(n),      xcl, A1);    // K1h*xl
                A1 = MFMA16(FR(n),      xch, A1);    // K1h*xh
                A1 = MFMA16(FR(15 + n), H1A, A1);    // R1l*h1h
                A1 = MFMA16(FR(10 + n), H1B, A1);    // R1h*h1l
                A1 = MFMA16(FR(10 + n), H1A, A1);    // R1h*h1h
                {   // layer 1 -> h1(t+1)
                    float iv = sigmoidf_(A1[0]);
                    float fv = sigmoidf_(A1[1]);
                    float gv = fmaxf(A1[2], 0.f);
                    float ov = sigmoidf_(A1[3]);
                    c1s[n] = fv * c1s[n] + iv * gv;
                    float h = ov * fmaxf(c1s[n], 0.f);
                    unsigned u = __float_as_uint(h);
                    h1h[woff + 4 * n] = (short)(unsigned short)(u >> 16);
                    h1l[woff + 4 * n] = (short)bf16_rne(h - __uint_as_float(u & 0xFFFF0000u));
                }
                f32x4 A2 = b2v[n];
                A2 = MFMA16(FR(25 + n), H1A, A2);    // K2l*h1h
                A2 = MFMA16(FR(20 + n), H1B, A2);    // K2h*h1l
                A2 = MFMA16(FR(20 + n), H1A, A2);    // K2h*h1h
                A2 = MFMA16(FR(35 + n), H2A, A2);    // R2l*h2h
                A2 = MFMA16(FR(30 + n), H2B, A2);    // R2h*h2l
                A2 = MFMA16(FR(30 + n), H2A, A2);    // R2h*h2h
                {   // layer 2 -> h2(t)
                    float iv = sigmoidf_(A2[0]);
                    float fv = sigmoidf_(A2[1]);
                    float gv = fmaxf(A2[2], 0.f);
                    float ov = sigmoidf_(A2[3]);
                    c2s[n] = fv * c2s[n] + iv * gv;
                    float h = ov * fmaxf(c2s[n], 0.f);
                    unsigned u = __float_as_uint(h);
                    h2h[woff + 4 * n] = (short)(unsigned short)(u >> 16);
                    h2l[woff + 4 * n] = (short)bf16_rne(h - __uint_as_float(u & 0xFFFF0000u));
                }
            }
            xch = xnh; xcl = xnl;
        }

        // ---- epilogue: L2 step T-1 -> dense head
        {
            bf16x8 H1A = *(bf16x8*)&h1h[hoff];
            bf16x8 H1B = *(bf16x8*)&h1l[hoff];
            bf16x8 H2A = *(bf16x8*)&h2h[hoff];
            bf16x8 H2B = *(bf16x8*)&h2l[hoff];
            float p = 0.f;
#pragma unroll
            for (int n = 0; n < 5; ++n) {
                f32x4 A2 = b2v[n];
                A2 = MFMA16(FR(25 + n), H1A, A2);
                A2 = MFMA16(FR(20 + n), H1B, A2);
                A2 = MFMA16(FR(20 + n), H1A, A2);
                A2 = MFMA16(FR(35 + n), H2A, A2);
                A2 = MFMA16(FR(30 + n), H2B, A2);
                A2 = MFMA16(FR(30 + n), H2A, A2);
                float iv = sigmoidf_(A2[0]);
                float fv = sigmoidf_(A2[1]);
                float gv = fmaxf(A2[2], 0.f);
                float ov = sigmoidf_(A2[3]);
                c2s[n] = fv * c2s[n] + iv * gv;
                p += ov * fmaxf(c2s[n], 0.f) * dwr[n];
            }
            p += __shfl_xor(p, 16);
            p += __shfl_xor(p, 32);
            if (q == 0) eo[(size_t)e * Bsz + b0 + s] = db[e] + p;
        }
#undef FR

    } else {
        // ================= fc1 path: one 64x64 tile per wave, LDS-free =================
        const int fid = blockIdx.x * 2 + (w - 2);
        const int m0 = (fid >> 6) * 64;
        const int n0 = (fid & 63) * 64;

        f32x4 acc[4][4];
#pragma unroll
        for (int mt = 0; mt < 4; ++mt)
#pragma unroll
            for (int nt = 0; nt < 4; ++nt) acc[mt][nt] = (f32x4){0.f, 0.f, 0.f, 0.f};

        const float* Arow[4];
#pragma unroll
        for (int mt = 0; mt < 4; ++mt)
            Arow[mt] = x + (size_t)(m0 + mt * 16 + s) * Dd + q * 8;
        const float* Wbase = W + (size_t)(q * 8) * Dd + n0 + s;

#pragma unroll 1
        for (int k0 = 0; k0 < Dd; k0 += 32) {
            float av[4][8];
#pragma unroll
            for (int mt = 0; mt < 4; ++mt) {
                *(float4*)&av[mt][0] = *(const float4*)(Arow[mt] + k0);
                *(float4*)&av[mt][4] = *(const float4*)(Arow[mt] + k0 + 4);
            }
            float wv[4][8];
#pragma unroll
            for (int j = 0; j < 8; ++j) {
                const float* wr = Wbase + (size_t)(k0 + j) * Dd;
#pragma unroll
                for (int nt = 0; nt < 4; ++nt) wv[nt][j] = wr[nt * 16];
            }
            bf16x8 Afh[4], Afl[4], Wfh[4], Wfl[4];
#pragma unroll
            for (int mt = 0; mt < 4; ++mt) split8(av[mt], Afh[mt], Afl[mt]);
#pragma unroll
            for (int nt = 0; nt < 4; ++nt) split8(wv[nt], Wfh[nt], Wfl[nt]);
#pragma unroll
            for (int mt = 0; mt < 4; ++mt)
#pragma unroll
                for (int nt = 0; nt < 4; ++nt) {
                    f32x4 a = acc[mt][nt];
                    a = MFMA16(Afl[mt], Wfh[nt], a);
                    a = MFMA16(Afh[mt], Wfl[nt], a);
                    a = MFMA16(Afh[mt], Wfh[nt], a);
                    acc[mt][nt] = a;
                }
        }

#pragma unroll
        for (int nt = 0; nt < 4; ++nt) {
            float bv = bias[n0 + nt * 16 + s];
#pragma unroll
            for (int mt = 0; mt < 4; ++mt)
#pragma unroll
                for (int r = 0; r < 4; ++r) {
                    int m = m0 + mt * 16 + q * 4 + r;
                    C[(size_t)m * Dd + n0 + nt * 16 + s] = fmaxf(acc[mt][nt][r] + bv, 0.f);
                }
        }
    }
}

// ---------------------------------------------------------------- gate: softmax(g @ gate_w + gb) + combine
__global__ __launch_bounds__(256) void gate_kernel(const float* __restrict__ g,
                                                   const float* __restrict__ gw,
                                                   const float* __restrict__ gb,
                                                   const float* __restrict__ eo,
                                                   float* __restrict__ out)
{
    int b = blockIdx.x;
    int tid = threadIdx.x;
    int lane = tid & 63;
    int wv = tid >> 6;

    float acc[16];
#pragma unroll
    for (int j = 0; j < 16; ++j) acc[j] = 0.f;

    const float* grow = g + (size_t)b * Dd;
#pragma unroll
    for (int it = 0; it < Dd / 256; ++it) {
        int d = tid + it * 256;
        float gv = grow[d];
        const float4* wr = (const float4*)(gw + (size_t)d * 16);
        float4 w0 = wr[0], w1 = wr[1], w2 = wr[2], w3 = wr[3];
        acc[0] += gv * w0.x;  acc[1] += gv * w0.y;  acc[2] += gv * w0.z;  acc[3] += gv * w0.w;
        acc[4] += gv * w1.x;  acc[5] += gv * w1.y;  acc[6] += gv * w1.z;  acc[7] += gv * w1.w;
        acc[8] += gv * w2.x;  acc[9] += gv * w2.y;  acc[10] += gv * w2.z; acc[11] += gv * w2.w;
        acc[12] += gv * w3.x; acc[13] += gv * w3.y; acc[14] += gv * w3.z; acc[15] += gv * w3.w;
    }

    __shared__ float red[64];
    __shared__ float logits[16];
#pragma unroll
    for (int j = 0; j < 16; ++j) {
        float v = acc[j];
#pragma unroll
        for (int m = 32; m >= 1; m >>= 1) v += __shfl_xor(v, m);
        if (lane == 0) red[wv * 16 + j] = v;
    }
    __syncthreads();
    if (tid < 16) {
        logits[tid] = gb[tid] + red[tid] + red[16 + tid] + red[32 + tid] + red[48 + tid];
    }
    __syncthreads();
    if (tid == 0) {
        float m = logits[0];
#pragma unroll
        for (int j = 1; j < 16; ++j) m = fmaxf(m, logits[j]);
        float ex[16], ssum = 0.f;
#pragma unroll
        for (int j = 0; j < 16; ++j) { ex[j] = __expf(logits[j] - m); ssum += ex[j]; }
        float inv = 1.f / ssum;
        float o = 0.f;
#pragma unroll
        for (int j = 0; j < 16; ++j) o += ex[j] * inv * eo[(size_t)j * Bsz + b];
        out[b] = o;
    }
}

// ----------------------------------------------------------------
extern "C" void kernel_launch(void* const* d_in, const int* in_sizes, int n_in,
                              void* d_out, int out_size, void* d_ws, size_t ws_size,
                              hipStream_t stream)
{
    const float* x     = (const float*)d_in[0];
    const float* gamma = (const float*)d_in[1];
    const float* beta  = (const float*)d_in[2];
    const float* mean  = (const float*)d_in[3];
    const float* var   = (const float*)d_in[4];
    const float* k1    = (const float*)d_in[5];
    const float* r1    = (const float*)d_in[6];
    const float* b1    = (const float*)d_in[7];
    const float* k2    = (const float*)d_in[8];
    const float* r2    = (const float*)d_in[9];
    const float* b2    = (const float*)d_in[10];
    const float* dw    = (const float*)d_in[11];
    const float* db    = (const float*)d_in[12];
    const float* fc1w  = (const float*)d_in[13];
    const float* fc1b  = (const float*)d_in[14];
    const float* gw    = (const float*)d_in[15];
    const float* gb    = (const float*)d_in[16];
    float* out = (float*)d_out;

    // workspace: 33.1 MB
    float* g = (float*)d_ws;                                        // 4,194,304 f (16 MB)
    unsigned short* xph = (unsigned short*)(g + (size_t)Bsz * Dd);  // 8 MB
    unsigned short* xpl = xph + (size_t)4194304;                    // 8 MB
    float* pw  = (float*)(xpl + (size_t)4194304);                   // 120,320 f
    float* eo  = pw + (size_t)Ee * PWE;                             // 16,384 f

    xpack_kernel<<<2048, 256, 0, stream>>>(x, gamma, beta, mean, var, xph, xpl);
    repack2_kernel<<<(Ee * PWE + 255) / 256, 256, 0, stream>>>(k1, r1, b1, k2, r2, b2, pw);
    fused_kernel<<<512, 256, 0, stream>>>(xph, xpl, pw, dw, db, eo, x, fc1w, fc1b, g);
    gate_kernel<<<Bsz, 256, 0, stream>>>(g, gw, gb, eo, out);
}